// Round 2
// baseline (1318.338 us; speedup 1.0000x reference)
//
#include <hip/hip_runtime.h>
#include <cstdint>
#include <cstddef>

#define T_LEN    16384
#define BATCH    8
#define BT       (BATCH * T_LEN)   // 131072
#define NLAYERS  40

typedef unsigned short ushort_t;
typedef unsigned int   uint_t;
typedef __attribute__((ext_vector_type(8))) short    short8;   // 8 bf16 (4 VGPR) MFMA frag
typedef __attribute__((ext_vector_type(4))) float    float4v;  // MFMA accumulator
typedef __attribute__((ext_vector_type(8))) _Float16 half8;    // 16B of fp16

__device__ __forceinline__ ushort_t f2bf(float f) {
    union { float f; uint_t i; } v; v.f = f;
    uint_t r = (v.i + 0x7FFFu + ((v.i >> 16) & 1u)) >> 16;
    return (ushort_t)r;
}
__device__ __forceinline__ float fast_rcp(float x) {
#if __has_builtin(__builtin_amdgcn_rcpf)
    return __builtin_amdgcn_rcpf(x);
#else
    return 1.f / x;
#endif
}
__device__ __forceinline__ float tanh_fast(float x) {
    float e = __expf(2.f * x);
    return 1.f - 2.f * fast_rcp(e + 1.f);
}
__device__ __forceinline__ float sigmoid_fast(float x) {
    return fast_rcp(1.f + __expf(-x));
}
__device__ __forceinline__ float4v mfma16(short8 a, short8 b, float4v c) {
    return __builtin_amdgcn_mfma_f32_16x16x32_bf16(a, b, c, 0, 0, 0);
}

// ---------------------------------------------------------------------------
// Weight prep: convert fp32 weights -> bf16 MFMA B-fragment layout.
// Frag layout: B[k = (lane>>4)*8 + j][n = lane&15], stored [frag][lane][8] bf16.
// ---------------------------------------------------------------------------
__global__ __launch_bounds__(256) void k_prep(
    const float* __restrict__ filt_w, const float* __restrict__ gate_w,
    const float* __restrict__ res_w,  const float* __restrict__ skip_w,
    const float* __restrict__ end1_w, const float* __restrict__ end2_w,
    const float* __restrict__ filt_b, const float* __restrict__ gate_b,
    const float* __restrict__ res_b,  const float* __restrict__ skip_b,
    const float* __restrict__ end1_b, const float* __restrict__ end2_b,
    ushort_t* __restrict__ wfgF, ushort_t* __restrict__ wrF,
    ushort_t* __restrict__ bsF,  ushort_t* __restrict__ e1F, ushort_t* __restrict__ e2F,
    float* __restrict__ bfg, float* __restrict__ brb, float* __restrict__ bsum,
    float* __restrict__ b1,  float* __restrict__ b2)
{
    const int gt = blockIdx.x * blockDim.x + threadIdx.x;
    const int gs = gridDim.x * blockDim.x;

    // WfgFrag: [i][nt(4)][ks(2)] -> frag f = (i*4+nt)*2+ks. nt0,1 = filt o=0..31; nt2,3 = gate.
    for (int e = gt; e < NLAYERS * 4 * 2 * 512; e += gs) {
        int j = e & 7, lane = (e >> 3) & 63, f = e >> 9;
        int ks = f & 1, nt = (f >> 1) & 3, i = f >> 3;
        int ln = lane & 15, q = lane >> 4, c = q * 8 + j;
        int o = (nt & 1) * 16 + ln;
        float v = (nt < 2) ? filt_w[((i * 32 + o) * 32 + c) * 2 + ks]
                           : gate_w[((i * 32 + o) * 32 + c) * 2 + ks];
        wfgF[e] = f2bf(v);
    }
    // WrFrag: [i][nt(2)][ks(2)]
    for (int e = gt; e < NLAYERS * 2 * 2 * 512; e += gs) {
        int j = e & 7, lane = (e >> 3) & 63, f = e >> 9;
        int ks = f & 1, nt = (f >> 1) & 1, i = f >> 2;
        int ln = lane & 15, q = lane >> 4, c = q * 8 + j;
        int o = nt * 16 + ln;
        wrF[e] = f2bf(res_w[((i * 32 + o) * 32 + c) * 2 + ks]);
    }
    // BsFrag: [ks80(80)][nt(16)]; ks80 = i*2 + tap (tap0 = t-d, tap1 = t)
    for (int e = gt; e < 80 * 16 * 512; e += gs) {
        int j = e & 7, lane = (e >> 3) & 63, f = e >> 9;
        int nt = f & 15, ks80 = f >> 4;
        int i = ks80 >> 1, tap = ks80 & 1;
        int ln = lane & 15, q = lane >> 4, c = q * 8 + j;
        int o = nt * 16 + ln;
        bsF[e] = f2bf(skip_w[((i * 256 + o) * 32 + c) * 2 + tap]);
    }
    // End1/End2 frags: [ks(8)][nt(16)]
    for (int e = gt; e < 8 * 16 * 512; e += gs) {
        int j = e & 7, lane = (e >> 3) & 63, f = e >> 9;
        int nt = f & 15, ks = f >> 4;
        int ln = lane & 15, q = lane >> 4;
        int k = ks * 32 + q * 8 + j;
        int o = nt * 16 + ln;
        e1F[e] = f2bf(end1_w[o * 256 + k]);
        e2F[e] = f2bf(end2_w[o * 256 + k]);
    }
    // Biases (fp32 passthrough / combine)
    for (int e = gt; e < NLAYERS * 64; e += gs) {
        int i = e >> 6, c = e & 63;
        bfg[e] = (c < 32) ? filt_b[i * 32 + c] : gate_b[i * 32 + (c - 32)];
    }
    for (int e = gt; e < NLAYERS * 32; e += gs) {
        int i = e >> 5, c = e & 31;
        brb[e] = res_b[i * 32 + c];
    }
    for (int e = gt; e < 256; e += gs) {
        float s = 0.f;
        for (int i = 0; i < NLAYERS; ++i) s += skip_b[i * 256 + e];
        bsum[e] = s;
        b1[e] = end1_b[e];
        b2[e] = end2_b[e];
    }
}

// ---------------------------------------------------------------------------
// Phase 1: input 1x1 conv  h0[bt][o] = sum_c w_in[o][c] * x[b][c][t] + b_in[o]
// ---------------------------------------------------------------------------
__global__ __launch_bounds__(256) void k_input(
    const float* __restrict__ x, const float* __restrict__ w_in,
    const float* __restrict__ b_in, _Float16* __restrict__ h16)
{
    __shared__ __align__(16) float ws[256 * 32];   // transposed [c][o], fp32
    for (int idx = threadIdx.x; idx < 256 * 32; idx += 256) {
        int o = idx >> 8, c = idx & 255;           // w_in flat = o*256 + c
        ws[c * 32 + o] = w_in[idx];
    }
    __syncthreads();
    const int bt = blockIdx.x * 256 + threadIdx.x;
    const float* xp = x + (size_t)(bt >> 14) * 256 * T_LEN + (bt & (T_LEN - 1));
    float acc[32];
#pragma unroll
    for (int o = 0; o < 32; ++o) acc[o] = b_in[o];
    for (int c = 0; c < 256; ++c) {
        float xv = xp[(size_t)c * T_LEN];
        const float4v* wr = (const float4v*)&ws[c * 32];
#pragma unroll
        for (int g = 0; g < 8; ++g) {
            float4v w4 = wr[g];
            acc[g * 4 + 0] += xv * w4[0];
            acc[g * 4 + 1] += xv * w4[1];
            acc[g * 4 + 2] += xv * w4[2];
            acc[g * 4 + 3] += xv * w4[3];
        }
    }
    half8* dst = (half8*)(h16 + (size_t)bt * 32);
#pragma unroll
    for (int g = 0; g < 4; ++g) {
        half8 v;
#pragma unroll
        for (int j = 0; j < 8; ++j) v[j] = (_Float16)acc[g * 8 + j];
        dst[g] = v;
    }
}

// ---------------------------------------------------------------------------
// Phase 2a: fused filter+gate -> z (MFMA 16x16x32, wave = 16 positions)
// ---------------------------------------------------------------------------
__global__ __launch_bounds__(256) void k_fg(
    const _Float16* __restrict__ h16, const ushort_t* __restrict__ wfgF,
    const float* __restrict__ bfg, ushort_t* __restrict__ zAll,
    int layer, int dil)
{
    const int w = threadIdx.x >> 6, lane = threadIdx.x & 63;
    const int ln = lane & 15, q = lane >> 4;
    const int bt0 = (blockIdx.x * 4 + w) * 16;
    const int m = bt0 + ln;
    const int koff = q * 8;

    short8 a0 = {0, 0, 0, 0, 0, 0, 0, 0}, a1;
    {
        half8 hv = *(const half8*)(h16 + (size_t)m * 32 + koff);
#pragma unroll
        for (int j = 0; j < 8; ++j) a1[j] = (short)f2bf((float)hv[j]);
    }
    if ((m & (T_LEN - 1)) >= dil) {
        half8 hv = *(const half8*)(h16 + (size_t)(m - dil) * 32 + koff);
#pragma unroll
        for (int j = 0; j < 8; ++j) a0[j] = (short)f2bf((float)hv[j]);
    }

    const short8* wf8 = (const short8*)wfgF;
    const float4v vzero = {0.f, 0.f, 0.f, 0.f};
    float4v acc[4];
#pragma unroll
    for (int nt = 0; nt < 4; ++nt) {
        float4v c = vzero;
        short8 b0 = wf8[(((size_t)layer * 4 + nt) * 2 + 0) * 64 + lane];
        short8 b1 = wf8[(((size_t)layer * 4 + nt) * 2 + 1) * 64 + lane];
        c = mfma16(a0, b0, c);
        c = mfma16(a1, b1, c);
        acc[nt] = c;
    }

    const float bF0 = bfg[layer * 64 + ln],      bF1 = bfg[layer * 64 + 16 + ln];
    const float bG0 = bfg[layer * 64 + 32 + ln], bG1 = bfg[layer * 64 + 48 + ln];
    ushort_t* zl = zAll + (size_t)layer * BT * 32;
#pragma unroll
    for (int r = 0; r < 4; ++r) {
        int row = bt0 + q * 4 + r;
        float z0 = tanh_fast(acc[0][r] + bF0) * sigmoid_fast(acc[2][r] + bG0);
        float z1 = tanh_fast(acc[1][r] + bF1) * sigmoid_fast(acc[3][r] + bG1);
        zl[(size_t)row * 32 + ln]      = f2bf(z0);
        zl[(size_t)row * 32 + 16 + ln] = f2bf(z1);
    }
}

// ---------------------------------------------------------------------------
// Phase 2b: residual update  h += Wr @ [z[t-d]; z[t]] + br  (MFMA + LDS transpose)
// ---------------------------------------------------------------------------
__global__ __launch_bounds__(256) void k_res(
    _Float16* __restrict__ h16, const ushort_t* __restrict__ zAll,
    const ushort_t* __restrict__ wrF, const float* __restrict__ brb,
    int layer, int dil)
{
    __shared__ float lds[4][16 * 35];   // per-wave 16x32 fp32 tile, row stride 35
    const int w = threadIdx.x >> 6, lane = threadIdx.x & 63;
    const int ln = lane & 15, q = lane >> 4;
    const int bt0 = (blockIdx.x * 4 + w) * 16;
    const int m = bt0 + ln;
    const int koff = q * 8;

    const ushort_t* zl = zAll + (size_t)layer * BT * 32;
    short8 a0 = {0, 0, 0, 0, 0, 0, 0, 0};
    if ((m & (T_LEN - 1)) >= dil)
        a0 = *(const short8*)(zl + (size_t)(m - dil) * 32 + koff);
    short8 a1 = *(const short8*)(zl + (size_t)m * 32 + koff);

    const short8* wr8 = (const short8*)wrF;
    const float4v vzero = {0.f, 0.f, 0.f, 0.f};
    float4v acc0 = vzero, acc1 = vzero;
    acc0 = mfma16(a0, wr8[(((size_t)layer * 2 + 0) * 2 + 0) * 64 + lane], acc0);
    acc0 = mfma16(a1, wr8[(((size_t)layer * 2 + 0) * 2 + 1) * 64 + lane], acc0);
    acc1 = mfma16(a0, wr8[(((size_t)layer * 2 + 1) * 2 + 0) * 64 + lane], acc1);
    acc1 = mfma16(a1, wr8[(((size_t)layer * 2 + 1) * 2 + 1) * 64 + lane], acc1);

    const float b0 = brb[layer * 32 + ln], b1 = brb[layer * 32 + 16 + ln];
#pragma unroll
    for (int r = 0; r < 4; ++r) {
        lds[w][(q * 4 + r) * 35 + ln]      = acc0[r] + b0;
        lds[w][(q * 4 + r) * 35 + 16 + ln] = acc1[r] + b1;
    }
    __syncthreads();
    const int p = lane & 15, g8 = lane >> 4;
    _Float16* hp = h16 + (size_t)(bt0 + p) * 32 + g8 * 8;
    half8 hv = *(const half8*)hp;
#pragma unroll
    for (int j = 0; j < 8; ++j)
        hv[j] = (_Float16)((float)hv[j] + lds[w][p * 35 + g8 * 8 + j]);
    *(half8*)hp = hv;
}

// ---------------------------------------------------------------------------
// Phase 3a: skip GEMM  skip[t][n] = relu( sum_{i,tap,c} Ws * z_i[...] + bsum[n] )
// M=131072, N=256, K=2560. Block tile 128x128, wave tile 64x64.
// ---------------------------------------------------------------------------
__global__ __launch_bounds__(256) void k_skip_gemm(
    const ushort_t* __restrict__ zAll, const ushort_t* __restrict__ bsF,
    const float* __restrict__ bsum, ushort_t* __restrict__ skipbuf)
{
    __shared__ __align__(16) ushort_t ldsB[8 * 512];   // 8 B-frags (8KB) per ks
    const int tid = threadIdx.x;
    const int w = tid >> 6, lane = tid & 63;
    const int wR = w >> 1, wC = w & 1;
    const int ln = lane & 15, q = lane >> 4, koff = q * 8;
    const int mBase = blockIdx.x * 128 + wR * 64;
    const int nBase = blockIdx.y * 128 + wC * 64;

    const float4v vzero = {0.f, 0.f, 0.f, 0.f};
    const short8 zero8 = {0, 0, 0, 0, 0, 0, 0, 0};
    float4v acc[4][4];
#pragma unroll
    for (int mt = 0; mt < 4; ++mt)
#pragma unroll
        for (int nt = 0; nt < 4; ++nt) acc[mt][nt] = vzero;

    for (int ks = 0; ks < 80; ++ks) {
        const short8* gsrc = (const short8*)bsF + ((size_t)ks * 16 + blockIdx.y * 8) * 64;
        short8 s0 = gsrc[tid];
        short8 s1 = gsrc[tid + 256];

        const int i = ks >> 1, tap = ks & 1;
        const int dil = 1 << (i % 10);
        const ushort_t* zl = zAll + (size_t)i * BT * 32;
        short8 a[4];
#pragma unroll
        for (int mt = 0; mt < 4; ++mt) {
            int m = mBase + mt * 16 + ln;
            if (tap) {
                a[mt] = *(const short8*)(zl + (size_t)m * 32 + koff);
            } else if ((m & (T_LEN - 1)) >= dil) {
                a[mt] = *(const short8*)(zl + (size_t)(m - dil) * 32 + koff);
            } else {
                a[mt] = zero8;
            }
        }
        ((short8*)ldsB)[tid] = s0;
        ((short8*)ldsB)[tid + 256] = s1;
        __syncthreads();
        short8 bfr[4];
#pragma unroll
        for (int nt = 0; nt < 4; ++nt)
            bfr[nt] = ((const short8*)ldsB)[(wC * 4 + nt) * 64 + lane];
#pragma unroll
        for (int mt = 0; mt < 4; ++mt)
#pragma unroll
            for (int nt = 0; nt < 4; ++nt)
                acc[mt][nt] = mfma16(a[mt], bfr[nt], acc[mt][nt]);
        __syncthreads();
    }

#pragma unroll
    for (int nt = 0; nt < 4; ++nt) {
        const int n = nBase + nt * 16 + ln;
        const float bias = bsum[n];
#pragma unroll
        for (int mt = 0; mt < 4; ++mt)
#pragma unroll
            for (int r = 0; r < 4; ++r) {
                int row = mBase + mt * 16 + q * 4 + r;
                float v = fmaxf(acc[mt][nt][r] + bias, 0.f);
                skipbuf[(size_t)row * 256 + n] = f2bf(v);
            }
    }
}

// ---------------------------------------------------------------------------
// Phase 3b: 256x256 GEMM (end1 / end2), K=256. A is bf16 [m][k].
// Output: bf16 to outB if outF==nullptr, else fp32 to outF.
// ---------------------------------------------------------------------------
__global__ __launch_bounds__(256) void k_gemm256(
    const ushort_t* __restrict__ A, const ushort_t* __restrict__ BF,
    const float* __restrict__ bias, ushort_t* __restrict__ outB,
    float* __restrict__ outF, int relu)
{
    __shared__ __align__(16) ushort_t ldsB[8 * 512];
    const int tid = threadIdx.x;
    const int w = tid >> 6, lane = tid & 63;
    const int wR = w >> 1, wC = w & 1;
    const int ln = lane & 15, q = lane >> 4, koff = q * 8;
    const int mBase = blockIdx.x * 128 + wR * 64;
    const int nBase = blockIdx.y * 128 + wC * 64;

    const float4v vzero = {0.f, 0.f, 0.f, 0.f};
    float4v acc[4][4];
#pragma unroll
    for (int mt = 0; mt < 4; ++mt)
#pragma unroll
        for (int nt = 0; nt < 4; ++nt) acc[mt][nt] = vzero;

    for (int ks = 0; ks < 8; ++ks) {
        const short8* gsrc = (const short8*)BF + ((size_t)ks * 16 + blockIdx.y * 8) * 64;
        short8 s0 = gsrc[tid];
        short8 s1 = gsrc[tid + 256];
        short8 a[4];
#pragma unroll
        for (int mt = 0; mt < 4; ++mt) {
            int m = mBase + mt * 16 + ln;
            a[mt] = *(const short8*)(A + (size_t)m * 256 + ks * 32 + koff);
        }
        ((short8*)ldsB)[tid] = s0;
        ((short8*)ldsB)[tid + 256] = s1;
        __syncthreads();
        short8 bfr[4];
#pragma unroll
        for (int nt = 0; nt < 4; ++nt)
            bfr[nt] = ((const short8*)ldsB)[(wC * 4 + nt) * 64 + lane];
#pragma unroll
        for (int mt = 0; mt < 4; ++mt)
#pragma unroll
            for (int nt = 0; nt < 4; ++nt)
                acc[mt][nt] = mfma16(a[mt], bfr[nt], acc[mt][nt]);
        __syncthreads();
    }

#pragma unroll
    for (int nt = 0; nt < 4; ++nt) {
        const int n = nBase + nt * 16 + ln;
        const float b = bias[n];
#pragma unroll
        for (int mt = 0; mt < 4; ++mt)
#pragma unroll
            for (int r = 0; r < 4; ++r) {
                int row = mBase + mt * 16 + q * 4 + r;
                float v = acc[mt][nt][r] + b;
                if (relu) v = fmaxf(v, 0.f);
                if (outF) outF[(size_t)row * 256 + n] = v;
                else      outB[(size_t)row * 256 + n] = f2bf(v);
            }
    }
}

// ---------------------------------------------------------------------------
extern "C" void kernel_launch(void* const* d_in, const int* in_sizes, int n_in,
                              void* d_out, int out_size, void* d_ws, size_t ws_size,
                              hipStream_t stream)
{
    (void)in_sizes; (void)n_in; (void)out_size; (void)ws_size;
    const float* x      = (const float*)d_in[0];
    const float* w_in   = (const float*)d_in[1];
    const float* b_in   = (const float*)d_in[2];
    const float* filt_w = (const float*)d_in[3];
    const float* filt_b = (const float*)d_in[4];
    const float* gate_w = (const float*)d_in[5];
    const float* gate_b = (const float*)d_in[6];
    const float* res_w  = (const float*)d_in[7];
    const float* res_b  = (const float*)d_in[8];
    const float* skip_w = (const float*)d_in[9];
    const float* skip_b = (const float*)d_in[10];
    const float* end1_w = (const float*)d_in[11];
    const float* end1_b = (const float*)d_in[12];
    const float* end2_w = (const float*)d_in[13];
    const float* end2_b = (const float*)d_in[14];

    char* ws = (char*)d_ws;
    size_t off = 0;
    auto alloc = [&](size_t bytes) {
        char* p = ws + off;
        off += (bytes + 255) & ~(size_t)255;
        return p;
    };
    ushort_t* zAll    = (ushort_t*)alloc((size_t)NLAYERS * BT * 32 * 2);  // 335.5 MB
    ushort_t* skipbuf = (ushort_t*)alloc((size_t)BT * 256 * 2);           // 67 MB
    _Float16* h16     = (_Float16*)alloc((size_t)BT * 32 * 2);            // 8.4 MB
    ushort_t* wfgF    = (ushort_t*)alloc((size_t)NLAYERS * 4 * 2 * 512 * 2);
    ushort_t* wrF     = (ushort_t*)alloc((size_t)NLAYERS * 2 * 2 * 512 * 2);
    ushort_t* bsF     = (ushort_t*)alloc((size_t)80 * 16 * 512 * 2);
    ushort_t* e1F     = (ushort_t*)alloc((size_t)8 * 16 * 512 * 2);
    ushort_t* e2F     = (ushort_t*)alloc((size_t)8 * 16 * 512 * 2);
    float* bfg  = (float*)alloc((size_t)NLAYERS * 64 * 4);
    float* brb  = (float*)alloc((size_t)NLAYERS * 32 * 4);
    float* bsum = (float*)alloc(256 * 4);
    float* b1   = (float*)alloc(256 * 4);
    float* b2   = (float*)alloc(256 * 4);
    ushort_t* out1 = zAll;   // zAll is dead after the skip GEMM; reuse for out1

    k_prep<<<256, 256, 0, stream>>>(filt_w, gate_w, res_w, skip_w, end1_w, end2_w,
                                    filt_b, gate_b, res_b, skip_b, end1_b, end2_b,
                                    wfgF, wrF, bsF, e1F, e2F, bfg, brb, bsum, b1, b2);
    k_input<<<BT / 256, 256, 0, stream>>>(x, w_in, b_in, h16);
    for (int i = 0; i < NLAYERS; ++i) {
        int dil = 1 << (i % 10);
        k_fg<<<BT / 64, 256, 0, stream>>>(h16, wfgF, bfg, zAll, i, dil);
        k_res<<<BT / 64, 256, 0, stream>>>(h16, zAll, wrF, brb, i, dil);
    }
    dim3 g3(BT / 128, 2);
    k_skip_gemm<<<g3, 256, 0, stream>>>(zAll, bsF, bsum, skipbuf);
    k_gemm256<<<g3, 256, 0, stream>>>(skipbuf, e1F, b1, out1, nullptr, 1);
    k_gemm256<<<g3, 256, 0, stream>>>(out1, e2F, b2, nullptr, (float*)d_out, 0);
}

// Round 4
// 1251.570 us; speedup vs baseline: 1.0533x; 1.0533x over previous
//
#include <hip/hip_runtime.h>
#include <cstdint>
#include <cstddef>

#define T_LEN    16384
#define BATCH    8
#define BT       (BATCH * T_LEN)   // 131072
#define NLAYERS  40

typedef unsigned short ushort_t;
typedef unsigned int   uint_t;
typedef __attribute__((ext_vector_type(8))) short    short8;   // 8 bf16 (4 VGPR) MFMA frag
typedef __attribute__((ext_vector_type(4))) float    float4v;  // MFMA accumulator
typedef __attribute__((ext_vector_type(8))) _Float16 half8;    // 16B of fp16

__device__ __forceinline__ ushort_t f2bf(float f) {
    union { float f; uint_t i; } v; v.f = f;
    uint_t r = (v.i + 0x7FFFu + ((v.i >> 16) & 1u)) >> 16;
    return (ushort_t)r;
}
__device__ __forceinline__ float fast_rcp(float x) {
#if __has_builtin(__builtin_amdgcn_rcpf)
    return __builtin_amdgcn_rcpf(x);
#else
    return 1.f / x;
#endif
}
__device__ __forceinline__ float tanh_fast(float x) {
    float e = __expf(2.f * x);
    return 1.f - 2.f * fast_rcp(e + 1.f);
}
__device__ __forceinline__ float sigmoid_fast(float x) {
    return fast_rcp(1.f + __expf(-x));
}
__device__ __forceinline__ float4v mfma16(short8 a, short8 b, float4v c) {
    return __builtin_amdgcn_mfma_f32_16x16x32_bf16(a, b, c, 0, 0, 0);
}

// ---------------------------------------------------------------------------
// Weight prep: convert fp32 weights -> bf16 MFMA B-fragment layout.
// Frag layout: B[k = (lane>>4)*8 + j][n = lane&15], stored [frag][lane][8] bf16.
// ---------------------------------------------------------------------------
__global__ __launch_bounds__(256) void k_prep(
    const float* __restrict__ filt_w, const float* __restrict__ gate_w,
    const float* __restrict__ res_w,  const float* __restrict__ skip_w,
    const float* __restrict__ end1_w, const float* __restrict__ end2_w,
    const float* __restrict__ filt_b, const float* __restrict__ gate_b,
    const float* __restrict__ res_b,  const float* __restrict__ skip_b,
    const float* __restrict__ end1_b, const float* __restrict__ end2_b,
    ushort_t* __restrict__ wfgF, ushort_t* __restrict__ wrF,
    ushort_t* __restrict__ bsF,  ushort_t* __restrict__ e1F, ushort_t* __restrict__ e2F,
    float* __restrict__ bfg, float* __restrict__ brb, float* __restrict__ bsum,
    float* __restrict__ b1,  float* __restrict__ b2)
{
    const int gt = blockIdx.x * blockDim.x + threadIdx.x;
    const int gs = gridDim.x * blockDim.x;

    // WfgFrag: [i][nt(4)][ks(2)] -> frag f = (i*4+nt)*2+ks. nt0,1 = filt o=0..31; nt2,3 = gate.
    for (int e = gt; e < NLAYERS * 4 * 2 * 512; e += gs) {
        int j = e & 7, lane = (e >> 3) & 63, f = e >> 9;
        int ks = f & 1, nt = (f >> 1) & 3, i = f >> 3;
        int ln = lane & 15, q = lane >> 4, c = q * 8 + j;
        int o = (nt & 1) * 16 + ln;
        float v = (nt < 2) ? filt_w[((i * 32 + o) * 32 + c) * 2 + ks]
                           : gate_w[((i * 32 + o) * 32 + c) * 2 + ks];
        wfgF[e] = f2bf(v);
    }
    // WrFrag: [i][nt(2)][ks(2)]
    for (int e = gt; e < NLAYERS * 2 * 2 * 512; e += gs) {
        int j = e & 7, lane = (e >> 3) & 63, f = e >> 9;
        int ks = f & 1, nt = (f >> 1) & 1, i = f >> 2;
        int ln = lane & 15, q = lane >> 4, c = q * 8 + j;
        int o = nt * 16 + ln;
        wrF[e] = f2bf(res_w[((i * 32 + o) * 32 + c) * 2 + ks]);
    }
    // BsFrag: [ks80(80)][nt(16)]; ks80 = i*2 + tap (tap0 = t-d, tap1 = t)
    for (int e = gt; e < 80 * 16 * 512; e += gs) {
        int j = e & 7, lane = (e >> 3) & 63, f = e >> 9;
        int nt = f & 15, ks80 = f >> 4;
        int i = ks80 >> 1, tap = ks80 & 1;
        int ln = lane & 15, q = lane >> 4, c = q * 8 + j;
        int o = nt * 16 + ln;
        bsF[e] = f2bf(skip_w[((i * 256 + o) * 32 + c) * 2 + tap]);
    }
    // End1/End2 frags: [ks(8)][nt(16)]
    for (int e = gt; e < 8 * 16 * 512; e += gs) {
        int j = e & 7, lane = (e >> 3) & 63, f = e >> 9;
        int nt = f & 15, ks = f >> 4;
        int ln = lane & 15, q = lane >> 4;
        int k = ks * 32 + q * 8 + j;
        int o = nt * 16 + ln;
        e1F[e] = f2bf(end1_w[o * 256 + k]);
        e2F[e] = f2bf(end2_w[o * 256 + k]);
    }
    // Biases
    for (int e = gt; e < NLAYERS * 64; e += gs) {
        int i = e >> 6, c = e & 63;
        bfg[e] = (c < 32) ? filt_b[i * 32 + c] : gate_b[i * 32 + (c - 32)];
    }
    for (int e = gt; e < NLAYERS * 32; e += gs) {
        int i = e >> 5, c = e & 31;
        brb[e] = res_b[i * 32 + c];
    }
    for (int e = gt; e < 256; e += gs) {
        float s = 0.f;
        for (int i = 0; i < NLAYERS; ++i) s += skip_b[i * 256 + e];
        bsum[e] = s;
        b1[e] = end1_b[e];
        b2[e] = end2_b[e];
    }
}

// ---------------------------------------------------------------------------
// Phase 1: input 1x1 conv  h0[bt][o] = sum_c w_in[o][c] * x[b][c][t] + b_in[o]
// ---------------------------------------------------------------------------
__global__ __launch_bounds__(256) void k_input(
    const float* __restrict__ x, const float* __restrict__ w_in,
    const float* __restrict__ b_in, _Float16* __restrict__ h16)
{
    __shared__ __align__(16) float ws[256 * 32];   // transposed [c][o], fp32
    for (int idx = threadIdx.x; idx < 256 * 32; idx += 256) {
        int o = idx >> 8, c = idx & 255;           // w_in flat = o*256 + c
        ws[c * 32 + o] = w_in[idx];
    }
    __syncthreads();
    const int bt = blockIdx.x * 256 + threadIdx.x;
    const float* xp = x + (size_t)(bt >> 14) * 256 * T_LEN + (bt & (T_LEN - 1));
    float acc[32];
#pragma unroll
    for (int o = 0; o < 32; ++o) acc[o] = b_in[o];
    for (int c = 0; c < 256; ++c) {
        float xv = xp[(size_t)c * T_LEN];
        const float4v* wr = (const float4v*)&ws[c * 32];
#pragma unroll
        for (int g = 0; g < 8; ++g) {
            float4v w4 = wr[g];
            acc[g * 4 + 0] += xv * w4[0];
            acc[g * 4 + 1] += xv * w4[1];
            acc[g * 4 + 2] += xv * w4[2];
            acc[g * 4 + 3] += xv * w4[3];
        }
    }
    half8* dst = (half8*)(h16 + (size_t)bt * 32);
#pragma unroll
    for (int g = 0; g < 4; ++g) {
        half8 v;
#pragma unroll
        for (int j = 0; j < 8; ++j) v[j] = (_Float16)acc[g * 8 + j];
        dst[g] = v;
    }
}

// ---------------------------------------------------------------------------
// Phase 2-start: fused filter+gate -> z for layer 0 only
// ---------------------------------------------------------------------------
__global__ __launch_bounds__(256) void k_fg(
    const _Float16* __restrict__ h16, const ushort_t* __restrict__ wfgF,
    const float* __restrict__ bfg, ushort_t* __restrict__ zAll,
    int layer, int dil)
{
    const int w = threadIdx.x >> 6, lane = threadIdx.x & 63;
    const int ln = lane & 15, q = lane >> 4;
    const int bt0 = (blockIdx.x * 4 + w) * 16;
    const int m = bt0 + ln;
    const int koff = q * 8;

    short8 a0 = {0, 0, 0, 0, 0, 0, 0, 0}, a1;
    {
        half8 hv = *(const half8*)(h16 + (size_t)m * 32 + koff);
#pragma unroll
        for (int j = 0; j < 8; ++j) a1[j] = (short)f2bf((float)hv[j]);
    }
    if ((m & (T_LEN - 1)) >= dil) {
        half8 hv = *(const half8*)(h16 + (size_t)(m - dil) * 32 + koff);
#pragma unroll
        for (int j = 0; j < 8; ++j) a0[j] = (short)f2bf((float)hv[j]);
    }

    const short8* wf8 = (const short8*)wfgF;
    const float4v vzero = {0.f, 0.f, 0.f, 0.f};
    float4v acc[4];
#pragma unroll
    for (int nt = 0; nt < 4; ++nt) {
        float4v c = vzero;
        short8 b0 = wf8[(((size_t)layer * 4 + nt) * 2 + 0) * 64 + lane];
        short8 b1 = wf8[(((size_t)layer * 4 + nt) * 2 + 1) * 64 + lane];
        c = mfma16(a0, b0, c);
        c = mfma16(a1, b1, c);
        acc[nt] = c;
    }

    const float bF0 = bfg[layer * 64 + ln],      bF1 = bfg[layer * 64 + 16 + ln];
    const float bG0 = bfg[layer * 64 + 32 + ln], bG1 = bfg[layer * 64 + 48 + ln];
    ushort_t* zl = zAll + (size_t)layer * BT * 32;
#pragma unroll
    for (int r = 0; r < 4; ++r) {
        int row = bt0 + q * 4 + r;
        float z0 = tanh_fast(acc[0][r] + bF0) * sigmoid_fast(acc[2][r] + bG0);
        float z1 = tanh_fast(acc[1][r] + bF1) * sigmoid_fast(acc[3][r] + bG1);
        zl[(size_t)row * 32 + ln]      = f2bf(z0);
        zl[(size_t)row * 32 + 16 + ln] = f2bf(z1);
    }
}

// ---------------------------------------------------------------------------
// Fused F(i) = res(i) + fg(i+1):
//   h_{i+1}[t]    = hin[t] + Wr_i @ [z_i[t-d]; z_i[t]] + br_i       (tile0)
//   h_{i+1}[t-d'] = recomputed in-block the same way                (tile1)
//   z_{i+1}[t]    = act(Wf_{i+1} @ [tile1; tile0] + b)
// Reads hin (layer i), writes hout (layer i+1): ping-pong, no cross-block race.
// Wave covers 32 positions (2 m-frags). Grid = BT/128.
// ---------------------------------------------------------------------------
__global__ __launch_bounds__(256) void k_resfg(
    const _Float16* __restrict__ hin, _Float16* __restrict__ hout,
    ushort_t* __restrict__ zAll,
    const ushort_t* __restrict__ wrF, const float* __restrict__ brb,
    const ushort_t* __restrict__ wfgF, const float* __restrict__ bfg,
    int layer, int dil, int dilN)
{
    __shared__ float lds[4][2][2][16 * 33];   // [wave][mt][tile][row*33+col], 33 KB
    const int w = threadIdx.x >> 6, lane = threadIdx.x & 63;
    const int ln = lane & 15, q = lane >> 4;
    const int koff = q * 8;
    const int bt0 = (blockIdx.x * 4 + w) * 32;
    const ushort_t* zl = zAll + (size_t)layer * BT * 32;
    ushort_t* zo = zAll + (size_t)(layer + 1) * BT * 32;
    const short8* wr8 = (const short8*)wrF;
    const short8* wf8 = (const short8*)wfgF;
    const float4v vzero = {0.f, 0.f, 0.f, 0.f};
    const short8 zero8 = {0, 0, 0, 0, 0, 0, 0, 0};

    // res B frags (layer i): nt 0..1 x ks 0..1 (shared by both tiles)
    const short8 rb00 = wr8[(((size_t)layer * 2 + 0) * 2 + 0) * 64 + lane];
    const short8 rb01 = wr8[(((size_t)layer * 2 + 0) * 2 + 1) * 64 + lane];
    const short8 rb10 = wr8[(((size_t)layer * 2 + 1) * 2 + 0) * 64 + lane];
    const short8 rb11 = wr8[(((size_t)layer * 2 + 1) * 2 + 1) * 64 + lane];
    const float br0 = brb[layer * 32 + ln], br1 = brb[layer * 32 + 16 + ln];

#pragma unroll
    for (int mt = 0; mt < 2; ++mt) {
        const int mb = bt0 + mt * 16;
        const int m = mb + ln;                 // A-frag row (this lane)
        const int tln = m & (T_LEN - 1);
        // tile0 inputs: z_i[m], z_i[m-d]
        short8 a1 = *(const short8*)(zl + (size_t)m * 32 + koff);
        short8 a0 = (tln >= dil) ? *(const short8*)(zl + (size_t)(m - dil) * 32 + koff) : zero8;
        float4v c0 = mfma16(a0, rb00, vzero); c0 = mfma16(a1, rb01, c0);
        float4v c1 = mfma16(a0, rb10, vzero); c1 = mfma16(a1, rb11, c1);
        // tile1 inputs: z_i[m-d'], z_i[m-d'-d]  (row invalid -> zero frag -> zero row)
        short8 p1 = (tln >= dilN)       ? *(const short8*)(zl + (size_t)(m - dilN) * 32 + koff)       : zero8;
        short8 p0 = (tln >= dilN + dil) ? *(const short8*)(zl + (size_t)(m - dilN - dil) * 32 + koff) : zero8;
        float4v d0 = mfma16(p0, rb00, vzero); d0 = mfma16(p1, rb01, d0);
        float4v d1 = mfma16(p0, rb10, vzero); d1 = mfma16(p1, rb11, d1);

        float* t0 = &lds[w][mt][0][0];
        float* t1 = &lds[w][mt][1][0];
#pragma unroll
        for (int r = 0; r < 4; ++r) {
            int row = q * 4 + r;               // local C-layout row
            int grow = mb + row;               // global position
            int tr = grow & (T_LEN - 1);
            float h0a = (float)hin[(size_t)grow * 32 + ln];
            float h0b = (float)hin[(size_t)grow * 32 + 16 + ln];
            t0[row * 33 + ln]      = c0[r] + br0 + h0a;
            t0[row * 33 + 16 + ln] = c1[r] + br1 + h0b;
            float hpa = 0.f, hpb = 0.f;
            if (tr >= dilN) {
                hpa = (float)hin[(size_t)(grow - dilN) * 32 + ln]      + d0[r] + br0;
                hpb = (float)hin[(size_t)(grow - dilN) * 32 + 16 + ln] + d1[r] + br1;
            }
            t1[row * 33 + ln]      = hpa;
            t1[row * 33 + 16 + ln] = hpb;
        }
    }
    __syncthreads();

    const int L1 = layer + 1;
    const float bF0 = bfg[L1 * 64 + ln],      bF1 = bfg[L1 * 64 + 16 + ln];
    const float bG0 = bfg[L1 * 64 + 32 + ln], bG1 = bfg[L1 * 64 + 48 + ln];
#pragma unroll
    for (int mt = 0; mt < 2; ++mt) {
        const int mb = bt0 + mt * 16;
        const float* t0 = &lds[w][mt][0][0];
        const float* t1 = &lds[w][mt][1][0];
        short8 fa1, fa0;
#pragma unroll
        for (int j = 0; j < 8; ++j) {
            fa1[j] = (short)f2bf(t0[ln * 33 + koff + j]);
            fa0[j] = (short)f2bf(t1[ln * 33 + koff + j]);
        }
        float4v acc[4];
#pragma unroll
        for (int nt = 0; nt < 4; ++nt) {
            float4v c = vzero;
            c = mfma16(fa0, wf8[(((size_t)L1 * 4 + nt) * 2 + 0) * 64 + lane], c);
            c = mfma16(fa1, wf8[(((size_t)L1 * 4 + nt) * 2 + 1) * 64 + lane], c);
            acc[nt] = c;
        }
#pragma unroll
        for (int r = 0; r < 4; ++r) {
            int row = mb + q * 4 + r;
            float z0 = tanh_fast(acc[0][r] + bF0) * sigmoid_fast(acc[2][r] + bG0);
            float z1 = tanh_fast(acc[1][r] + bF1) * sigmoid_fast(acc[3][r] + bG1);
            zo[(size_t)row * 32 + ln]      = f2bf(z0);
            zo[(size_t)row * 32 + 16 + ln] = f2bf(z1);
        }
        // write h_{i+1}[mb..mb+15] as fp16 (lane ln = row, q = 8-col chunk)
        half8 hv;
#pragma unroll
        for (int j = 0; j < 8; ++j) hv[j] = (_Float16)t0[ln * 33 + q * 8 + j];
        *(half8*)(hout + (size_t)(mb + ln) * 32 + q * 8) = hv;
    }
}

// ---------------------------------------------------------------------------
// Phase 3a: skip GEMM, full-N blocks. Block 512 thr (8 waves, 2x4), tile 128x256.
// Per layer: stage 32 B-frags (32 KB), 32 MFMA/wave per barrier-pair.
// ---------------------------------------------------------------------------
__global__ __launch_bounds__(512) void k_skip_gemm(
    const ushort_t* __restrict__ zAll, const ushort_t* __restrict__ bsF,
    const float* __restrict__ bsum, ushort_t* __restrict__ skipbuf)
{
    __shared__ __align__(16) ushort_t ldsB[32 * 512];   // 32 KB
    const int tid = threadIdx.x;
    const int w = tid >> 6, lane = tid & 63;
    const int wR = w >> 2, wC = w & 3;
    const int ln = lane & 15, q = lane >> 4, koff = q * 8;
    const int mBase = blockIdx.x * 128 + wR * 64;

    const float4v vzero = {0.f, 0.f, 0.f, 0.f};
    const short8 zero8 = {0, 0, 0, 0, 0, 0, 0, 0};
    float4v acc[4][4];
#pragma unroll
    for (int mt = 0; mt < 4; ++mt)
#pragma unroll
        for (int nt = 0; nt < 4; ++nt) acc[mt][nt] = vzero;

    short8* lb = (short8*)ldsB;
    for (int i = 0; i < NLAYERS; ++i) {
        // stage B: 32 frags for layer i (contiguous 2048 short8)
        const short8* gsrc = (const short8*)(bsF + (size_t)i * 32 * 512);
        short8 s0 = gsrc[tid], s1 = gsrc[tid + 512], s2 = gsrc[tid + 1024], s3 = gsrc[tid + 1536];

        const int dil = 1 << (i % 10);
        const ushort_t* zl = zAll + (size_t)i * BT * 32;
        short8 a1[4], a0[4];
#pragma unroll
        for (int mt = 0; mt < 4; ++mt) {
            int m = mBase + mt * 16 + ln;
            int tln = m & (T_LEN - 1);
            a1[mt] = *(const short8*)(zl + (size_t)m * 32 + koff);
            a0[mt] = (tln >= dil) ? *(const short8*)(zl + (size_t)(m - dil) * 32 + koff) : zero8;
        }
        lb[tid] = s0; lb[tid + 512] = s1; lb[tid + 1024] = s2; lb[tid + 1536] = s3;
        __syncthreads();
        short8 b0[4], b1[4];
#pragma unroll
        for (int nt = 0; nt < 4; ++nt) {
            b0[nt] = lb[(wC * 4 + nt) * 64 + lane];        // tap0 (z[t-d])
            b1[nt] = lb[(16 + wC * 4 + nt) * 64 + lane];   // tap1 (z[t])
        }
#pragma unroll
        for (int mt = 0; mt < 4; ++mt)
#pragma unroll
            for (int nt = 0; nt < 4; ++nt) {
                acc[mt][nt] = mfma16(a0[mt], b0[nt], acc[mt][nt]);
                acc[mt][nt] = mfma16(a1[mt], b1[nt], acc[mt][nt]);
            }
        __syncthreads();
    }

#pragma unroll
    for (int nt = 0; nt < 4; ++nt) {
        const int n = wC * 64 + nt * 16 + ln;
        const float bias = bsum[n];
#pragma unroll
        for (int mt = 0; mt < 4; ++mt)
#pragma unroll
            for (int r = 0; r < 4; ++r) {
                int row = mBase + mt * 16 + q * 4 + r;
                float v = fmaxf(acc[mt][nt][r] + bias, 0.f);
                skipbuf[(size_t)row * 256 + n] = f2bf(v);
            }
    }
}

// ---------------------------------------------------------------------------
// Phase 3b: fused end1+end2. Block 512 thr, tile 128x256 (full N), K=256 each.
// out1 stays in LDS as A-fragments (never touches HBM).
// ---------------------------------------------------------------------------
__global__ __launch_bounds__(512) void k_end(
    const ushort_t* __restrict__ skipbuf, const ushort_t* __restrict__ e1F,
    const ushort_t* __restrict__ e2F, const float* __restrict__ b1,
    const float* __restrict__ b2, float* __restrict__ out)
{
    __shared__ __align__(16) ushort_t ldsS[16 * 512];   // 16 KB B staging
    __shared__ __align__(16) ushort_t ldsA[64 * 512];   // 64 KB A2 frags
    const int tid = threadIdx.x;
    const int w = tid >> 6, lane = tid & 63;
    const int wR = w >> 2, wC = w & 3;
    const int ln = lane & 15, q = lane >> 4, koff = q * 8;
    const int mBase = blockIdx.x * 128 + wR * 64;

    const float4v vzero = {0.f, 0.f, 0.f, 0.f};
    float4v acc[4][4];
#pragma unroll
    for (int mt = 0; mt < 4; ++mt)
#pragma unroll
        for (int nt = 0; nt < 4; ++nt) acc[mt][nt] = vzero;

    short8* ls = (short8*)ldsS;
    // ---- GEMM1: out1 = relu(skip @ W1 + b1) ----
    for (int ks = 0; ks < 8; ++ks) {
        const short8* gsrc = (const short8*)(e1F + (size_t)ks * 16 * 512);
        short8 s0 = gsrc[tid], s1 = gsrc[tid + 512];
        short8 a[4];
#pragma unroll
        for (int mt = 0; mt < 4; ++mt) {
            int m = mBase + mt * 16 + ln;
            a[mt] = *(const short8*)(skipbuf + (size_t)m * 256 + ks * 32 + koff);
        }
        ls[tid] = s0; ls[tid + 512] = s1;
        __syncthreads();
        short8 bfr[4];
#pragma unroll
        for (int nt = 0; nt < 4; ++nt) bfr[nt] = ls[(wC * 4 + nt) * 64 + lane];
#pragma unroll
        for (int mt = 0; mt < 4; ++mt)
#pragma unroll
            for (int nt = 0; nt < 4; ++nt)
                acc[mt][nt] = mfma16(a[mt], bfr[nt], acc[mt][nt]);
        __syncthreads();
    }
    // epilogue1: relu + bias -> ldsA in A-frag layout (bf16)
#pragma unroll
    for (int nt = 0; nt < 4; ++nt) {
        const int col = wC * 64 + nt * 16 + ln;
        const float bb = b1[col];
        const int fk = col >> 5;
        const int l2hi = ((col >> 3) & 3) << 4;
        const int j = col & 7;
#pragma unroll
        for (int mt = 0; mt < 4; ++mt) {
            const int fr = wR * 4 + mt;
#pragma unroll
            for (int r = 0; r < 4; ++r) {
                int lane2 = (q * 4 + r) | l2hi;
                float v = fmaxf(acc[mt][nt][r] + bb, 0.f);
                ldsA[((fr * 8 + fk) * 64 + lane2) * 8 + j] = f2bf(v);
            }
        }
    }
    __syncthreads();
    // ---- GEMM2: out = out1 @ W2 + b2 ----
#pragma unroll
    for (int mt = 0; mt < 4; ++mt)
#pragma unroll
        for (int nt = 0; nt < 4; ++nt) acc[mt][nt] = vzero;
    for (int ks = 0; ks < 8; ++ks) {
        const short8* gsrc = (const short8*)(e2F + (size_t)ks * 16 * 512);
        short8 s0 = gsrc[tid], s1 = gsrc[tid + 512];
        short8 a[4];
#pragma unroll
        for (int mt = 0; mt < 4; ++mt)
            a[mt] = ((const short8*)ldsA)[((size_t)(wR * 4 + mt) * 8 + ks) * 64 + lane];
        ls[tid] = s0; ls[tid + 512] = s1;
        __syncthreads();
        short8 bfr[4];
#pragma unroll
        for (int nt = 0; nt < 4; ++nt) bfr[nt] = ls[(wC * 4 + nt) * 64 + lane];
#pragma unroll
        for (int mt = 0; mt < 4; ++mt)
#pragma unroll
            for (int nt = 0; nt < 4; ++nt)
                acc[mt][nt] = mfma16(a[mt], bfr[nt], acc[mt][nt]);
        __syncthreads();
    }
#pragma unroll
    for (int nt = 0; nt < 4; ++nt) {
        const int n = wC * 64 + nt * 16 + ln;
        const float bb = b2[n];
#pragma unroll
        for (int mt = 0; mt < 4; ++mt)
#pragma unroll
            for (int r = 0; r < 4; ++r) {
                int row = mBase + mt * 16 + q * 4 + r;
                out[(size_t)row * 256 + n] = acc[mt][nt][r] + bb;
            }
    }
}

// ---------------------------------------------------------------------------
extern "C" void kernel_launch(void* const* d_in, const int* in_sizes, int n_in,
                              void* d_out, int out_size, void* d_ws, size_t ws_size,
                              hipStream_t stream)
{
    (void)in_sizes; (void)n_in; (void)out_size; (void)ws_size;
    const float* x      = (const float*)d_in[0];
    const float* w_in   = (const float*)d_in[1];
    const float* b_in   = (const float*)d_in[2];
    const float* filt_w = (const float*)d_in[3];
    const float* filt_b = (const float*)d_in[4];
    const float* gate_w = (const float*)d_in[5];
    const float* gate_b = (const float*)d_in[6];
    const float* res_w  = (const float*)d_in[7];
    const float* res_b  = (const float*)d_in[8];
    const float* skip_w = (const float*)d_in[9];
    const float* skip_b = (const float*)d_in[10];
    const float* end1_w = (const float*)d_in[11];
    const float* end1_b = (const float*)d_in[12];
    const float* end2_w = (const float*)d_in[13];
    const float* end2_b = (const float*)d_in[14];

    char* ws = (char*)d_ws;
    size_t off = 0;
    auto alloc = [&](size_t bytes) {
        char* p = ws + off;
        off += (bytes + 255) & ~(size_t)255;
        return p;
    };
    // Footprint discipline: R3 failed because total ws use (421.5 MB) exceeded
    // what R2 proved safe (413.1 MB) -> overflow corrupted harness pristine
    // copies (first call right, every restored call deterministically wrong).
    // Fix: overlay the h ping-pong buffers inside skipbuf (skipbuf is written
    // only after all k_resfg launches are done; h is dead by then).
    // New total ~404.7 MB < 413.1 MB.
    ushort_t* zAll    = (ushort_t*)alloc((size_t)NLAYERS * BT * 32 * 2);  // 335.5 MB
    ushort_t* skipbuf = (ushort_t*)alloc((size_t)BT * 256 * 2);           // 67 MB
    _Float16* hA      = (_Float16*)skipbuf;                               // overlay
    _Float16* hB      = (_Float16*)(skipbuf + (size_t)BT * 32);           // overlay
    ushort_t* wfgF    = (ushort_t*)alloc((size_t)NLAYERS * 4 * 2 * 512 * 2);
    ushort_t* wrF     = (ushort_t*)alloc((size_t)NLAYERS * 2 * 2 * 512 * 2);
    ushort_t* bsF     = (ushort_t*)alloc((size_t)80 * 16 * 512 * 2);
    ushort_t* e1F     = (ushort_t*)alloc((size_t)8 * 16 * 512 * 2);
    ushort_t* e2F     = (ushort_t*)alloc((size_t)8 * 16 * 512 * 2);
    float* bfg  = (float*)alloc((size_t)NLAYERS * 64 * 4);
    float* brb  = (float*)alloc((size_t)NLAYERS * 32 * 4);
    float* bsum = (float*)alloc(256 * 4);
    float* b1   = (float*)alloc(256 * 4);
    float* b2   = (float*)alloc(256 * 4);

    k_prep<<<256, 256, 0, stream>>>(filt_w, gate_w, res_w, skip_w, end1_w, end2_w,
                                    filt_b, gate_b, res_b, skip_b, end1_b, end2_b,
                                    wfgF, wrF, bsF, e1F, e2F, bfg, brb, bsum, b1, b2);
    k_input<<<BT / 256, 256, 0, stream>>>(x, w_in, b_in, hA);
    k_fg<<<BT / 64, 256, 0, stream>>>(hA, wfgF, bfg, zAll, 0, 1);
    for (int i = 0; i < NLAYERS - 1; ++i) {
        const _Float16* hin = (i & 1) ? hB : hA;
        _Float16*       ho  = (i & 1) ? hA : hB;
        int dil  = 1 << (i % 10);
        int dilN = 1 << ((i + 1) % 10);
        k_resfg<<<BT / 128, 256, 0, stream>>>(hin, ho, zAll, wrF, brb, wfgF, bfg,
                                              i, dil, dilN);
    }
    k_skip_gemm<<<BT / 128, 512, 0, stream>>>(zAll, bsF, bsum, skipbuf);
    k_end<<<BT / 128, 512, 0, stream>>>(skipbuf, e1F, e2F, b1, b2, (float*)d_out);
}